// Round 2
// baseline (132.168 us; speedup 1.0000x reference)
//
#include <hip/hip_runtime.h>

#define NRULE 100
#define NB    32
#define NE    15000
#define NTOT  (NB * NE)   // 480000
#define HD    16
#define KMID  128
#define LN_EPS 1e-5f
#define RCHUNK 20         // rc loads kept in flight per chunk

// Precompute c[k] = b1[k] + sum_h rel[h] * W1[(H+h)*128 + k]  (rel = relation_emb[all_r[0]])
__global__ void precompute_c_kernel(const int* __restrict__ all_r,
                                    const float* __restrict__ relemb,
                                    const float* __restrict__ W1,
                                    const float* __restrict__ b1,
                                    float* __restrict__ cvec)
{
    const int k = threadIdx.x;
    if (k >= KMID) return;
    const int r = all_r[0];
    float t = b1[k];
#pragma unroll
    for (int h = 0; h < HD; ++h)
        t = fmaf(relemb[r * HD + h], W1[(HD + h) * KMID + k], t);
    cvec[k] = t;
}

__global__ __launch_bounds__(256, 8) void predictor_main_kernel(
    const int*   __restrict__ rc,     // [R, B*E]
    const float* __restrict__ remb,   // [R, 16]
    const float* __restrict__ ln_g,
    const float* __restrict__ ln_b,
    const float* __restrict__ W1,     // [32, 128] row-major; rows 0..15 used here
    const float* __restrict__ W2,     // [128]
    const float* __restrict__ b2,     // [1]
    const float* __restrict__ bias,   // [E]
    const float* __restrict__ cvec,   // [128] precomputed
    float* __restrict__ out)          // [B*E]
{
    const int tid = blockIdx.x * blockDim.x + threadIdx.x;   // one element per thread
    if (tid >= NTOT) return;

    float acc[HD];
#pragma unroll
    for (int h = 0; h < HD; ++h) acc[h] = 0.f;
    float ws = 0.f;

    const int* rcp = rc + tid;
#pragma unroll
    for (int r0 = 0; r0 < NRULE; r0 += RCHUNK) {
        int v[RCHUNK];
#pragma unroll
        for (int i = 0; i < RCHUNK; ++i)
            v[i] = rcp[(r0 + i) * NTOT];                     // 20 independent loads in flight
#pragma unroll
        for (int i = 0; i < RCHUNK; ++i) {
            const float f = (float)v[i];
            ws += f;
#pragma unroll
            for (int h = 0; h < HD; ++h)
                acc[h] = fmaf(f, remb[(r0 + i) * HD + h], acc[h]);  // remb uniform -> SGPR
        }
    }

    // LayerNorm over H=16 + ReLU, in place into acc
    {
        float mu = 0.f;
#pragma unroll
        for (int h = 0; h < HD; ++h) mu += acc[h];
        mu *= (1.f / HD);
        float var = 0.f;
#pragma unroll
        for (int h = 0; h < HD; ++h) {
            const float d = acc[h] - mu;
            var = fmaf(d, d, var);
        }
        var *= (1.f / HD);
        const float ri = rsqrtf(var + LN_EPS);
#pragma unroll
        for (int h = 0; h < HD; ++h)
            acc[h] = fmaxf(fmaf((acc[h] - mu) * ri, ln_g[h], ln_b[h]), 0.f);
    }

    // MLP: o = W2^T relu(W1[0:16]^T acc + c) + b2
    float o = b2[0];
#pragma unroll 1
    for (int kc = 0; kc < KMID; kc += 16) {
        float t[16];
#pragma unroll
        for (int kk = 0; kk < 16; ++kk) t[kk] = cvec[kc + kk];
#pragma unroll
        for (int h = 0; h < HD; ++h) {
            const float a = acc[h];
#pragma unroll
            for (int kk = 0; kk < 16; ++kk)
                t[kk] = fmaf(a, W1[h * KMID + kc + kk], t[kk]);  // uniform -> SGPR
        }
#pragma unroll
        for (int kk = 0; kk < 16; ++kk)
            o = fmaf(fmaxf(t[kk], 0.f), W2[kc + kk], o);
    }

    o = (ws > 0.f) ? o : 0.f;
    out[tid] = o + bias[tid % NE];
}

extern "C" void kernel_launch(void* const* d_in, const int* in_sizes, int n_in,
                              void* d_out, int out_size, void* d_ws, size_t ws_size,
                              hipStream_t stream)
{
    const int*   all_r  = (const int*)d_in[1];
    const int*   rc     = (const int*)d_in[2];
    const float* remb   = (const float*)d_in[3];
    const float* relemb = (const float*)d_in[4];
    const float* ln_g   = (const float*)d_in[5];
    const float* ln_b   = (const float*)d_in[6];
    const float* W1     = (const float*)d_in[7];
    const float* b1     = (const float*)d_in[8];
    const float* W2     = (const float*)d_in[9];
    const float* b2     = (const float*)d_in[10];
    const float* bias   = (const float*)d_in[11];
    float* out  = (float*)d_out;
    float* cvec = (float*)d_ws;

    hipLaunchKernelGGL(precompute_c_kernel, dim3(1), dim3(128), 0, stream,
                       all_r, relemb, W1, b1, cvec);

    const int blocks = (NTOT + 255) / 256;   // 1875
    hipLaunchKernelGGL(predictor_main_kernel, dim3(blocks), dim3(256), 0, stream,
                       rc, remb, ln_g, ln_b, W1, W2, b2, bias, cvec, out);
}

// Round 3
// 74.829 us; speedup vs baseline: 1.7663x; 1.7663x over previous
//
#include <hip/hip_runtime.h>

#define NRULE 100
#define NB    32
#define NE    15000
#define NTOT  (NB * NE)   // 480000
#define HD    16
#define KMID  128
#define LN_EPS 1e-5f
#define RCHUNK 10         // rc loads kept in flight per chunk

// Precompute c[k] = b1[k] + sum_h rel[h] * W1[(H+h)*128 + k]  (rel = relation_emb[all_r[0]])
__global__ void precompute_c_kernel(const long long* __restrict__ all_r,
                                    const float* __restrict__ relemb,
                                    const float* __restrict__ W1,
                                    const float* __restrict__ b1,
                                    float* __restrict__ cvec)
{
    const int k = threadIdx.x;
    if (k >= KMID) return;
    const int r = (int)all_r[0];
    float t = b1[k];
#pragma unroll
    for (int h = 0; h < HD; ++h)
        t = fmaf(relemb[r * HD + h], W1[(HD + h) * KMID + k], t);
    cvec[k] = t;
}

__global__ __launch_bounds__(256) void predictor_main_kernel(
    const int*   __restrict__ rc,     // [R, B*E]
    const float* __restrict__ remb,   // [R, 16]
    const float* __restrict__ ln_g,
    const float* __restrict__ ln_b,
    const float* __restrict__ W1,     // [32, 128] row-major; rows 0..15 used here
    const float* __restrict__ W2,     // [128]
    const float* __restrict__ b2,     // [1]
    const float* __restrict__ bias,   // [E]
    const float* __restrict__ cvec,   // [128] precomputed
    float* __restrict__ out)          // [B*E]
{
    const int tid = blockIdx.x * blockDim.x + threadIdx.x;   // one element per thread
    if (tid >= NTOT) return;

    float acc[HD];
#pragma unroll
    for (int h = 0; h < HD; ++h) acc[h] = 0.f;
    float ws = 0.f;

    const int* rcp = rc + tid;
#pragma unroll 2
    for (int r0 = 0; r0 < NRULE; r0 += RCHUNK) {
        int v[RCHUNK];
#pragma unroll
        for (int i = 0; i < RCHUNK; ++i)
            v[i] = rcp[(r0 + i) * NTOT];                     // 10 independent loads in flight
#pragma unroll
        for (int i = 0; i < RCHUNK; ++i) {
            const float f = (float)v[i];
            ws += f;
#pragma unroll
            for (int h = 0; h < HD; ++h)
                acc[h] = fmaf(f, remb[(r0 + i) * HD + h], acc[h]);  // remb uniform -> SGPR
        }
    }

    // LayerNorm over H=16 + ReLU, in place into acc
    {
        float mu = 0.f;
#pragma unroll
        for (int h = 0; h < HD; ++h) mu += acc[h];
        mu *= (1.f / HD);
        float var = 0.f;
#pragma unroll
        for (int h = 0; h < HD; ++h) {
            const float d = acc[h] - mu;
            var = fmaf(d, d, var);
        }
        var *= (1.f / HD);
        const float ri = rsqrtf(var + LN_EPS);
#pragma unroll
        for (int h = 0; h < HD; ++h)
            acc[h] = fmaxf(fmaf((acc[h] - mu) * ri, ln_g[h], ln_b[h]), 0.f);
    }

    // MLP: o = W2^T relu(W1[0:16]^T acc + c) + b2, mid dim in chunks of 8 to cap live regs
    float o = b2[0];
#pragma unroll 1
    for (int kc = 0; kc < KMID; kc += 8) {
        float t[8];
#pragma unroll
        for (int kk = 0; kk < 8; ++kk) t[kk] = cvec[kc + kk];
#pragma unroll
        for (int h = 0; h < HD; ++h) {
            const float a = acc[h];
#pragma unroll
            for (int kk = 0; kk < 8; ++kk)
                t[kk] = fmaf(a, W1[h * KMID + kc + kk], t[kk]);  // uniform -> SGPR
        }
#pragma unroll
        for (int kk = 0; kk < 8; ++kk)
            o = fmaf(fmaxf(t[kk], 0.f), W2[kc + kk], o);
    }

    o = (ws > 0.f) ? o : 0.f;
    out[tid] = o + bias[tid % NE];
}

extern "C" void kernel_launch(void* const* d_in, const int* in_sizes, int n_in,
                              void* d_out, int out_size, void* d_ws, size_t ws_size,
                              hipStream_t stream)
{
    const long long* all_r = (const long long*)d_in[1];
    const int*   rc     = (const int*)d_in[2];
    const float* remb   = (const float*)d_in[3];
    const float* relemb = (const float*)d_in[4];
    const float* ln_g   = (const float*)d_in[5];
    const float* ln_b   = (const float*)d_in[6];
    const float* W1     = (const float*)d_in[7];
    const float* b1     = (const float*)d_in[8];
    const float* W2     = (const float*)d_in[9];
    const float* b2     = (const float*)d_in[10];
    const float* bias   = (const float*)d_in[11];
    float* out  = (float*)d_out;
    float* cvec = (float*)d_ws;

    hipLaunchKernelGGL(precompute_c_kernel, dim3(1), dim3(128), 0, stream,
                       all_r, relemb, W1, b1, cvec);

    const int blocks = (NTOT + 255) / 256;   // 1875
    hipLaunchKernelGGL(predictor_main_kernel, dim3(blocks), dim3(256), 0, stream,
                       rc, remb, ln_g, ln_b, W1, W2, b2, bias, cvec, out);
}